// Round 1
// baseline (4790.821 us; speedup 1.0000x reference)
//
#include <hip/hip_runtime.h>
#include <math.h>

#define NNODES 883
#define RP 8
#define BB 8
#define DIMS_ 160
#define HID_ 320
#define RMAX (BB*NNODES)   // 7064 packed rows

// ---------------- patch assignment: logits, softmax, argmax, node_soft ----------------
__global__ __launch_bounds__(128)
void patch_kernel(const float* __restrict__ node_table,
                  const float* __restrict__ patch_emb,
                  float* __restrict__ probs_st,
                  float* __restrict__ nsoft,
                  int* __restrict__ patch_ids) {
  int n = blockIdx.x * blockDim.x + threadIdx.x;
  if (n >= NNODES) return;
  float nt[32];
#pragma unroll
  for (int j = 0; j < 32; ++j) nt[j] = node_table[n*32 + j];
  float lg[8];
#pragma unroll
  for (int r = 0; r < 8; ++r) {
    float a = 0.f;
#pragma unroll
    for (int j = 0; j < 32; ++j) a += nt[j] * patch_emb[r*32 + j];
    lg[r] = a;
  }
  float m = lg[0];
#pragma unroll
  for (int r = 1; r < 8; ++r) m = fmaxf(m, lg[r]);
  float e[8]; float s = 0.f;
#pragma unroll
  for (int r = 0; r < 8; ++r) { e[r] = expf(lg[r] - m); s += e[r]; }
  float p[8];
#pragma unroll
  for (int r = 0; r < 8; ++r) p[r] = e[r] / s;
  int am = 0; float best = p[0];
#pragma unroll
  for (int r = 1; r < 8; ++r) if (p[r] > best) { best = p[r]; am = r; }
  patch_ids[n] = am;
#pragma unroll
  for (int r = 0; r < 8; ++r) {
    float hard = (r == am) ? 1.f : 0.f;
    probs_st[n*8 + r] = (hard - p[r]) + p[r];
  }
#pragma unroll
  for (int j = 0; j < 32; ++j) {
    float a = 0.f;
#pragma unroll
    for (int r = 0; r < 8; ++r) a += p[r] * patch_emb[r*32 + j];
    nsoft[n*32 + j] = a;
  }
}

// ---------------- serial scan: positions within patch, offsets, counts ----------------
__global__ void scan_kernel(const int* __restrict__ patch_ids,
                            int* __restrict__ posArr, int* __restrict__ pk,
                            int* __restrict__ invp, int* __restrict__ cnt,
                            int* __restrict__ offs, int* __restrict__ cntmax) {
  if (threadIdx.x != 0 || blockIdx.x != 0) return;
  int c[8];
#pragma unroll
  for (int r = 0; r < 8; ++r) c[r] = 0;
  for (int n = 0; n < NNODES; ++n) {
    int r = patch_ids[n];
    posArr[n] = c[r]++;
  }
  int o = 0, mx = 0;
#pragma unroll
  for (int r = 0; r < 8; ++r) {
    offs[r] = o; cnt[r] = c[r]; o += c[r];
    if (c[r] > mx) mx = c[r];
  }
  cntmax[0] = mx;
  for (int n = 0; n < NNODES; ++n) {
    int r = patch_ids[n];
    int q = offs[r] + posArr[n];
    pk[n] = q; invp[q] = n;
  }
}

// ---------------- embedding: conv + tod + dow + node_soft into packed pf ----------------
__global__ __launch_bounds__(160)
void embed_kernel(const float* __restrict__ x, const int* __restrict__ te,
                  const float* __restrict__ convW, const float* __restrict__ convB,
                  const float* __restrict__ tod, const float* __restrict__ dow,
                  const float* __restrict__ nsoft, const int* __restrict__ pk,
                  float* __restrict__ pf) {
  int n = blockIdx.x, b = blockIdx.y, t = threadIdx.x;
  __shared__ float xs[3][12];
  if (t < 12) {
    int l = t;
    xs[0][l] = x[(b*12 + l)*NNODES + n];
    int base = ((b*12 + l)*NNODES + n)*2;
    xs[1][l] = (float)te[base]     / 288.0f;
    xs[2][l] = (float)te[base + 1] / 7.0f;
  }
  __syncthreads();
  int row = b*NNODES + pk[n];
  float val;
  if (t < 64) {
    float a = convB[t];
#pragma unroll
    for (int c = 0; c < 3; ++c)
#pragma unroll
      for (int l = 0; l < 12; ++l)
        a += xs[c][l] * convW[t*36 + c*12 + l];
    val = a;
  } else if (t < 96) {
    int ti = te[((b*12 + 11)*NNODES + n)*2 + 0];
    val = tod[ti*32 + (t - 64)];
  } else if (t < 128) {
    int dw = te[((b*12 + 11)*NNODES + n)*2 + 1];
    val = dow[dw*32 + (t - 96)];
  } else {
    val = nsoft[n*32 + (t - 128)];
  }
  pf[row*DIMS_ + t] = val;
}

// ---------------- layernorm over DIMS per row ----------------
__global__ __launch_bounds__(160)
void ln_kernel(const float* __restrict__ src, float* __restrict__ dst,
               const float* __restrict__ g, const float* __restrict__ bt) {
  __shared__ float red[160];
  int row = blockIdx.x, t = threadIdx.x;
  float v = src[row*DIMS_ + t];
  red[t] = v; __syncthreads();
  for (int off = 128; off > 0; off >>= 1) {
    if (t < off && t + off < DIMS_) red[t] += red[t + off];
    __syncthreads();
  }
  float mu = red[0] / 160.0f;
  __syncthreads();
  float d = v - mu;
  red[t] = d*d; __syncthreads();
  for (int off = 128; off > 0; off >>= 1) {
    if (t < off && t + off < DIMS_) red[t] += red[t + off];
    __syncthreads();
  }
  float var = red[0] / 160.0f;
  dst[row*DIMS_ + t] = d / sqrtf(var + 1e-5f) * g[t] + bt[t];
}

// ---------------- generic matmul: C[M,N] = act(X[M,K] @ W[K,N] + bias), optional += ----------------
template<int ROWS, int K, int ACT, bool RESID>
__global__ __launch_bounds__(256)
void matmul_kernel(const float* __restrict__ X, const float* __restrict__ W,
                   const float* __restrict__ bias, float* __restrict__ C,
                   int M, int N) {
  constexpr int STR = K + 5;
  __shared__ float Xs[ROWS * STR];
  int rowbase = blockIdx.x * ROWS;
  for (int idx = threadIdx.x; idx < ROWS*K; idx += 256) {
    int r = idx / K, k = idx - r*K;
    int gr = rowbase + r;
    Xs[r*STR + k] = (gr < M) ? X[gr*K + k] : 0.f;
  }
  __syncthreads();
  constexpr int CG = 256 / ROWS;        // col groups
  int r  = (int)threadIdx.x % ROWS;
  int cg = (int)threadIdx.x / ROWS;
  int grow = rowbase + r;
  bool valid = grow < M;
  const float* Xr = &Xs[r*STR];
  for (int c0 = cg*4; c0 < N; c0 += CG*4) {
    float4 acc;
    acc.x = bias[c0]; acc.y = bias[c0+1]; acc.z = bias[c0+2]; acc.w = bias[c0+3];
#pragma unroll 8
    for (int k = 0; k < K; ++k) {
      float xv = Xr[k];
      float4 w4 = *reinterpret_cast<const float4*>(&W[(size_t)k*N + c0]);
      acc.x += xv * w4.x; acc.y += xv * w4.y;
      acc.z += xv * w4.z; acc.w += xv * w4.w;
    }
    if (ACT == 1) {
      acc.x = 0.5f*acc.x*(1.f + erff(acc.x*0.70710678118654752f));
      acc.y = 0.5f*acc.y*(1.f + erff(acc.y*0.70710678118654752f));
      acc.z = 0.5f*acc.z*(1.f + erff(acc.z*0.70710678118654752f));
      acc.w = 0.5f*acc.w*(1.f + erff(acc.w*0.70710678118654752f));
    }
    if (valid) {
      float* Cr = &C[(size_t)grow*N + c0];
      if (RESID) { Cr[0] += acc.x; Cr[1] += acc.y; Cr[2] += acc.z; Cr[3] += acc.w; }
      else       { Cr[0]  = acc.x; Cr[1]  = acc.y; Cr[2]  = acc.z; Cr[3]  = acc.w; }
    }
  }
}

// ---------------- intra-patch attention (dense within each patch) ----------------
__global__ __launch_bounds__(256)
void intra_attn(const float* __restrict__ qb, const float* __restrict__ kb,
                const float* __restrict__ vb, float* __restrict__ ab,
                const int* __restrict__ cnt, const int* __restrict__ offs) {
  int r = blockIdx.y, b = blockIdx.z;
  int L = cnt[r];
  int qbase = blockIdx.x * 32;
  if (qbase >= L) return;
  int bo = b*NNODES + offs[r];
  __shared__ float qs[160];
  __shared__ float sc[896];
  __shared__ float red[256];
  int t = threadIdx.x;
  int qend = min(qbase + 32, L);
  const float scale = 1.0f / sqrtf(160.0f);
  for (int qi = qbase; qi < qend; ++qi) {
    if (t < 160) qs[t] = qb[(size_t)(bo + qi)*DIMS_ + t];
    __syncthreads();
    float lmax = -INFINITY;
    for (int j = t; j < L; j += 256) {
      const float* kr = &kb[(size_t)(bo + j)*DIMS_];
      float a = 0.f;
#pragma unroll 8
      for (int d = 0; d < 160; ++d) a += qs[d]*kr[d];
      a *= scale;
      sc[j] = a;
      lmax = fmaxf(lmax, a);
    }
    red[t] = lmax; __syncthreads();
    for (int off = 128; off > 0; off >>= 1) {
      if (t < off) red[t] = fmaxf(red[t], red[t + off]);
      __syncthreads();
    }
    float m = red[0]; __syncthreads();
    float lsum = 0.f;
    for (int j = t; j < L; j += 256) {
      float e = expf(sc[j] - m);
      sc[j] = e; lsum += e;
    }
    red[t] = lsum; __syncthreads();
    for (int off = 128; off > 0; off >>= 1) {
      if (t < off) red[t] += red[t + off];
      __syncthreads();
    }
    float invs = 1.0f / red[0];
    __syncthreads();
    if (t < 160) {
      float a = 0.f;
      for (int j = 0; j < L; ++j) a += sc[j] * vb[(size_t)(bo + j)*DIMS_ + t];
      ab[(size_t)(bo + qi)*DIMS_ + t] = a * invs;
    }
    __syncthreads();
  }
}

// ---------------- inter-patch attention (<=8 keys per position) ----------------
__global__ __launch_bounds__(64)
void inter_attn(const float* __restrict__ qb, const float* __restrict__ kb,
                const float* __restrict__ vb, float* __restrict__ ab,
                const int* __restrict__ cnt, const int* __restrict__ offs,
                const int* __restrict__ cntmax) {
  int p = blockIdx.x, b = blockIdx.y;
  if (p >= cntmax[0]) return;
  int t = threadIdx.x;
  __shared__ int rows[8];
  __shared__ int nvs;
  __shared__ float sc[8][8];
  __shared__ float w[8][8];
  if (t == 0) {
    int nv = 0;
    for (int r = 0; r < 8; ++r)
      if (p < cnt[r]) rows[nv++] = b*NNODES + offs[r] + p;
    nvs = nv;
  }
  __syncthreads();
  int nv = nvs;
  const float scale = 1.0f / sqrtf(160.0f);
  int i = t >> 3, j = t & 7;
  if (i < nv && j < nv) {
    const float* qr = &qb[(size_t)rows[i]*DIMS_];
    const float* kr = &kb[(size_t)rows[j]*DIMS_];
    float a = 0.f;
#pragma unroll 8
    for (int d = 0; d < 160; ++d) a += qr[d]*kr[d];
    sc[i][j] = a * scale;
  }
  __syncthreads();
  if (t < nv) {
    float m = -INFINITY;
    for (int jj = 0; jj < nv; ++jj) m = fmaxf(m, sc[t][jj]);
    float s = 0.f;
    for (int jj = 0; jj < nv; ++jj) { float e = expf(sc[t][jj] - m); w[t][jj] = e; s += e; }
    float invs = 1.0f / s;
    for (int jj = 0; jj < nv; ++jj) w[t][jj] *= invs;
  }
  __syncthreads();
  for (int d = t; d < 160; d += 64) {
    for (int i2 = 0; i2 < nv; ++i2) {
      float a = 0.f;
      for (int j2 = 0; j2 < nv; ++j2) a += w[i2][j2] * vb[(size_t)rows[j2]*DIMS_ + d];
      ab[(size_t)rows[i2]*DIMS_ + d] = a;
    }
  }
}

// ---------------- final projection: pred[b,o,n,0] ----------------
__global__ __launch_bounds__(256)
void out_kernel(const float* __restrict__ pf, const float* __restrict__ outW,
                const float* __restrict__ outB, const int* __restrict__ pk,
                float* __restrict__ out) {
  int idx = blockIdx.x*256 + threadIdx.x;
  if (idx >= BB*12*NNODES) return;
  int n = idx % NNODES;
  int rest = idx / NNODES;
  int o = rest % 12;
  int b = rest / 12;
  int row = b*NNODES + pk[n];
  float a = outB[o];
#pragma unroll 8
  for (int d = 0; d < 160; ++d) a += pf[(size_t)row*DIMS_ + d] * outW[o*DIMS_ + d];
  out[idx] = a;
}

extern "C" void kernel_launch(void* const* d_in, const int* in_sizes, int n_in,
                              void* d_out, int out_size, void* d_ws, size_t ws_size,
                              hipStream_t stream) {
  const float* x         = (const float*)d_in[0];
  const int*   te        = (const int*)d_in[1];
  const float* patch_emb = (const float*)d_in[2];
  const float* node_tab  = (const float*)d_in[3];
  const float* tod_emb   = (const float*)d_in[4];
  const float* dow_emb   = (const float*)d_in[5];
  const float* conv_W    = (const float*)d_in[6];
  const float* conv_b    = (const float*)d_in[7];
  const float* ln_scale  = (const float*)d_in[8];
  const float* ln_bias   = (const float*)d_in[9];
  const float* attn_W    = (const float*)d_in[10];
  const float* attn_b    = (const float*)d_in[11];
  const float* mlp_W1    = (const float*)d_in[12];
  const float* mlp_b1    = (const float*)d_in[13];
  const float* mlp_W2    = (const float*)d_in[14];
  const float* mlp_b2    = (const float*)d_in[15];
  const float* out_W     = (const float*)d_in[16];
  const float* out_b     = (const float*)d_in[17];

  float* out = (float*)d_out;
  float* probs_st = out + BB*12*NNODES;   // pred is 8*12*883 = 84768 floats

  float* ws = (float*)d_ws;
  float* pf  = ws;
  float* xn  = pf  + (size_t)RMAX*DIMS_;
  float* qb  = xn  + (size_t)RMAX*DIMS_;
  float* kb  = qb  + (size_t)RMAX*DIMS_;
  float* vb  = kb  + (size_t)RMAX*DIMS_;
  float* ab2 = vb  + (size_t)RMAX*DIMS_;
  float* hb  = ab2 + (size_t)RMAX*DIMS_;
  float* nsoft = hb + (size_t)RMAX*HID_;
  int* ib = (int*)(nsoft + NNODES*32);
  int* patch_ids = ib;
  int* posArr = patch_ids + NNODES;
  int* pk     = posArr + NNODES;
  int* invp   = pk + NNODES;
  int* cnt    = invp + NNODES;
  int* offs   = cnt + 8;
  int* cntmax = offs + 8;

  patch_kernel<<<(NNODES + 127)/128, 128, 0, stream>>>(node_tab, patch_emb, probs_st, nsoft, patch_ids);
  scan_kernel<<<1, 1, 0, stream>>>(patch_ids, posArr, pk, invp, cnt, offs, cntmax);
  embed_kernel<<<dim3(NNODES, BB), 160, 0, stream>>>(x, te, conv_W, conv_b, tod_emb, dow_emb, nsoft, pk, pf);

  const int GRID64 = (RMAX + 63)/64;    // 111
  const int GRID32 = (RMAX + 31)/32;    // 221

  for (int l = 0; l < 3; ++l) {
    for (int a = 0; a < 2; ++a) {
      int wb = l*2 + a;
      // LN before attention (idx 0 for intra, 2 for inter)
      ln_kernel<<<RMAX, 160, 0, stream>>>(pf, xn,
          ln_scale + (size_t)(l*4 + a*2)*DIMS_, ln_bias + (size_t)(l*4 + a*2)*DIMS_);
      // q, k, v projections
      const float* Wbase = attn_W + (size_t)wb*4*DIMS_*DIMS_;
      const float* bbase = attn_b + (size_t)wb*4*DIMS_;
      matmul_kernel<64,160,0,false><<<GRID64, 256, 0, stream>>>(xn, Wbase + 0*DIMS_*DIMS_, bbase + 0*DIMS_, qb, RMAX, DIMS_);
      matmul_kernel<64,160,0,false><<<GRID64, 256, 0, stream>>>(xn, Wbase + 1*DIMS_*DIMS_, bbase + 1*DIMS_, kb, RMAX, DIMS_);
      matmul_kernel<64,160,0,false><<<GRID64, 256, 0, stream>>>(xn, Wbase + 2*DIMS_*DIMS_, bbase + 2*DIMS_, vb, RMAX, DIMS_);
      // attention
      if (a == 0)
        intra_attn<<<dim3(28, 8, BB), 256, 0, stream>>>(qb, kb, vb, ab2, cnt, offs);
      else
        inter_attn<<<dim3(NNODES, BB), 64, 0, stream>>>(qb, kb, vb, ab2, cnt, offs, cntmax);
      // output projection, residual into pf
      matmul_kernel<64,160,0,true><<<GRID64, 256, 0, stream>>>(ab2, Wbase + 3*DIMS_*DIMS_, bbase + 3*DIMS_, pf, RMAX, DIMS_);
      // LN before MLP (idx 1 for intra, 3 for inter)
      ln_kernel<<<RMAX, 160, 0, stream>>>(pf, xn,
          ln_scale + (size_t)(l*4 + a*2 + 1)*DIMS_, ln_bias + (size_t)(l*4 + a*2 + 1)*DIMS_);
      // MLP
      matmul_kernel<64,160,1,false><<<GRID64, 256, 0, stream>>>(xn, mlp_W1 + (size_t)wb*DIMS_*HID_, mlp_b1 + (size_t)wb*HID_, hb, RMAX, HID_);
      matmul_kernel<32,320,0,true><<<GRID32, 256, 0, stream>>>(hb, mlp_W2 + (size_t)wb*HID_*DIMS_, mlp_b2 + (size_t)wb*DIMS_, pf, RMAX, DIMS_);
    }
  }

  out_kernel<<<(BB*12*NNODES + 255)/256, 256, 0, stream>>>(pf, out_W, out_b, pk, out);
}

// Round 2
// 1737.514 us; speedup vs baseline: 2.7573x; 2.7573x over previous
//
#include <hip/hip_runtime.h>
#include <math.h>

#define NNODES 883
#define BB 8
#define DIMS_ 160
#define HID_ 320
#define RMAX (BB*NNODES)   // 7064 packed rows

// ---------------- patch assignment ----------------
__global__ __launch_bounds__(128)
void patch_kernel(const float* __restrict__ node_table,
                  const float* __restrict__ patch_emb,
                  float* __restrict__ probs_st,
                  float* __restrict__ nsoft,
                  int* __restrict__ patch_ids) {
  int n = blockIdx.x * blockDim.x + threadIdx.x;
  if (n >= NNODES) return;
  float nt[32];
#pragma unroll
  for (int j = 0; j < 32; ++j) nt[j] = node_table[n*32 + j];
  float lg[8];
#pragma unroll
  for (int r = 0; r < 8; ++r) {
    float a = 0.f;
#pragma unroll
    for (int j = 0; j < 32; ++j) a += nt[j] * patch_emb[r*32 + j];
    lg[r] = a;
  }
  float m = lg[0];
#pragma unroll
  for (int r = 1; r < 8; ++r) m = fmaxf(m, lg[r]);
  float e[8]; float s = 0.f;
#pragma unroll
  for (int r = 0; r < 8; ++r) { e[r] = expf(lg[r] - m); s += e[r]; }
  float p[8];
#pragma unroll
  for (int r = 0; r < 8; ++r) p[r] = e[r] / s;
  int am = 0; float best = p[0];
#pragma unroll
  for (int r = 1; r < 8; ++r) if (p[r] > best) { best = p[r]; am = r; }
  patch_ids[n] = am;
#pragma unroll
  for (int r = 0; r < 8; ++r) {
    float hard = (r == am) ? 1.f : 0.f;
    probs_st[n*8 + r] = (hard - p[r]) + p[r];
  }
#pragma unroll
  for (int j = 0; j < 32; ++j) {
    float a = 0.f;
#pragma unroll
    for (int r = 0; r < 8; ++r) a += p[r] * patch_emb[r*32 + j];
    nsoft[n*32 + j] = a;
  }
}

// ---------------- parallel scan ----------------
__global__ __launch_bounds__(1024)
void scan_kernel(const int* __restrict__ patch_ids,
                 int* __restrict__ pk, int* __restrict__ cnt,
                 int* __restrict__ offs, int* __restrict__ cntmax) {
  __shared__ int pid_s[NNODES];
  __shared__ int cnt_s[8], offs_s[8];
  int t = threadIdx.x;
  if (t < 8) cnt_s[t] = 0;
  for (int n = t; n < NNODES; n += 1024) pid_s[n] = patch_ids[n];
  __syncthreads();
  int p = -1, pos = 0;
  if (t < NNODES) {
    p = pid_s[t];
    atomicAdd(&cnt_s[p], 1);
    for (int m = 0; m < t; ++m) pos += (pid_s[m] == p) ? 1 : 0;
  }
  __syncthreads();
  if (t == 0) {
    int o = 0, mx = 0;
#pragma unroll
    for (int r = 0; r < 8; ++r) {
      offs_s[r] = o; offs[r] = o; o += cnt_s[r];
      cnt[r] = cnt_s[r];
      if (cnt_s[r] > mx) mx = cnt_s[r];
    }
    cntmax[0] = mx;
  }
  __syncthreads();
  if (t < NNODES) pk[t] = offs_s[p] + pos;
}

// ---------------- embedding ----------------
__global__ __launch_bounds__(160)
void embed_kernel(const float* __restrict__ x, const int* __restrict__ te,
                  const float* __restrict__ convW, const float* __restrict__ convB,
                  const float* __restrict__ tod, const float* __restrict__ dow,
                  const float* __restrict__ nsoft, const int* __restrict__ pk,
                  float* __restrict__ pf) {
  int n = blockIdx.x, b = blockIdx.y, t = threadIdx.x;
  __shared__ float xs[3][12];
  if (t < 12) {
    int l = t;
    xs[0][l] = x[(b*12 + l)*NNODES + n];
    int base = ((b*12 + l)*NNODES + n)*2;
    xs[1][l] = (float)te[base]     / 288.0f;
    xs[2][l] = (float)te[base + 1] / 7.0f;
  }
  __syncthreads();
  int row = b*NNODES + pk[n];
  float val;
  if (t < 64) {
    float a = convB[t];
#pragma unroll
    for (int c = 0; c < 3; ++c)
#pragma unroll
      for (int l = 0; l < 12; ++l)
        a += xs[c][l] * convW[t*36 + c*12 + l];
    val = a;
  } else if (t < 96) {
    int ti = te[((b*12 + 11)*NNODES + n)*2 + 0];
    val = tod[ti*32 + (t - 64)];
  } else if (t < 128) {
    int dw = te[((b*12 + 11)*NNODES + n)*2 + 1];
    val = dow[dw*32 + (t - 96)];
  } else {
    val = nsoft[n*32 + (t - 128)];
  }
  pf[row*DIMS_ + t] = val;
}

// ---------------- fused (optional LN) matmul: 32 rows x 160 cols per block ----------------
template<int K, int ACT, bool RESID, bool LN>
__global__ __launch_bounds__(256)
void matmul_ln(const float* __restrict__ X, const float* __restrict__ W,
               const float* __restrict__ bias, float* __restrict__ C,
               const float* __restrict__ g, const float* __restrict__ bt,
               int M, int Nfull, int Cstride,
               size_t Wystep, size_t Cystep, int bystep, int colstep) {
  constexpr int ROWS = 32;
  constexpr int STR = K + 1;
  __shared__ float Xs[ROWS * STR];
  __shared__ float gs[LN ? K : 1];
  __shared__ float bs[LN ? K : 1];
  int tid = threadIdx.x;
  int rowbase = blockIdx.x * ROWS;
  int y = blockIdx.y;
  W    += (size_t)y * Wystep;
  C    += (size_t)y * Cystep;
  bias += (size_t)y * bystep;
  int coloff = y * colstep;

  for (int idx = tid; idx < ROWS*(K/4); idx += 256) {
    int r = idx / (K/4), d4 = idx % (K/4);
    int gr = rowbase + r;
    float4 v;
    if (gr < M) v = *(const float4*)&X[(size_t)gr*K + d4*4];
    else        v = float4{0.f,0.f,0.f,0.f};
    Xs[r*STR + d4*4 + 0] = v.x; Xs[r*STR + d4*4 + 1] = v.y;
    Xs[r*STR + d4*4 + 2] = v.z; Xs[r*STR + d4*4 + 3] = v.w;
  }
  if (LN) {
    for (int k = tid; k < K; k += 256) { gs[k] = g[k]; bs[k] = bt[k]; }
  }
  __syncthreads();

  if (LN) {
    int r = tid >> 3, i = tid & 7;
    float s = 0.f, ss = 0.f;
    for (int k = i; k < K; k += 8) { float v = Xs[r*STR + k]; s += v; ss += v*v; }
    s += __shfl_xor(s, 1, 8); ss += __shfl_xor(ss, 1, 8);
    s += __shfl_xor(s, 2, 8); ss += __shfl_xor(ss, 2, 8);
    s += __shfl_xor(s, 4, 8); ss += __shfl_xor(ss, 4, 8);
    float mu = s / (float)K;
    float var = ss / (float)K - mu*mu;
    float rsig = rsqrtf(var + 1e-5f);
    for (int k = i; k < K; k += 8)
      Xs[r*STR + k] = (Xs[r*STR + k] - mu) * rsig * gs[k] + bs[k];
    __syncthreads();
  }

  int r = tid & 31, cg = tid >> 5;
  int gr = rowbase + r;
  bool valid = gr < M;
  const float* Xr = &Xs[r*STR];
#pragma unroll
  for (int i2 = 0; i2 < 5; ++i2) {
    int c = (cg + 8*i2) * 4;
    int gc = coloff + c;
    float4 acc = *(const float4*)&bias[c + coloff];
#pragma unroll 8
    for (int k = 0; k < K; ++k) {
      float xv = Xr[k];
      float4 w4 = *(const float4*)&W[(size_t)k*Nfull + gc];
      acc.x += xv * w4.x; acc.y += xv * w4.y;
      acc.z += xv * w4.z; acc.w += xv * w4.w;
    }
    if (ACT == 1) {
      acc.x = 0.5f*acc.x*(1.f + erff(acc.x*0.70710678118654752f));
      acc.y = 0.5f*acc.y*(1.f + erff(acc.y*0.70710678118654752f));
      acc.z = 0.5f*acc.z*(1.f + erff(acc.z*0.70710678118654752f));
      acc.w = 0.5f*acc.w*(1.f + erff(acc.w*0.70710678118654752f));
    }
    if (valid) {
      float* Cr = &C[(size_t)gr*Cstride + gc];
      if (RESID) {
        float4 old = *(const float4*)Cr;
        old.x += acc.x; old.y += acc.y; old.z += acc.z; old.w += acc.w;
        *(float4*)Cr = old;
      } else {
        *(float4*)Cr = acc;
      }
    }
  }
}

// ---------------- intra-patch attention ----------------
#define QT 16
#define KT 32
#define SMAX 256
#define TSTR 164

__global__ __launch_bounds__(256)
void intra_attn(const float* __restrict__ qb, const float* __restrict__ kb,
                const float* __restrict__ vb, float* __restrict__ ab,
                const int* __restrict__ cnt, const int* __restrict__ offs) {
  int r = blockIdx.y, b = blockIdx.z;
  int L = cnt[r];
  int qbase = blockIdx.x * QT;
  if (qbase >= L) return;
  int nq = min(QT, L - qbase);
  int bo = b*NNODES + offs[r];
  __shared__ float Qs[QT*TSTR];
  __shared__ float KVs[KT*TSTR];
  __shared__ float S[QT*SMAX];
  int tid = threadIdx.x;
  const float scale = 0.07905694150420949f;

  for (int idx = tid; idx < nq*40; idx += 256) {
    int q = idx/40, d4 = idx%40;
    *(float4*)&Qs[q*TSTR + d4*4] =
        *(const float4*)&qb[(size_t)(bo+qbase+q)*DIMS_ + d4*4];
  }

  int nkt = (L + KT - 1)/KT;
  for (int kt = 0; kt < nkt; ++kt) {
    int jbase = kt*KT;
    int nj = min(KT, L - jbase);
    __syncthreads();
    for (int idx = tid; idx < nj*40; idx += 256) {
      int j = idx/40, d4 = idx%40;
      *(float4*)&KVs[j*TSTR + d4*4] =
          *(const float4*)&kb[(size_t)(bo+jbase+j)*DIMS_ + d4*4];
    }
    __syncthreads();
#pragma unroll
    for (int p = tid; p < 512; p += 256) {
      int q = p >> 5, j = p & 31;
      if (q < nq && j < nj) {
        const float* Qr = &Qs[q*TSTR];
        const float* Kr = &KVs[j*TSTR];
        float ax=0.f, ay=0.f, az=0.f, aw=0.f;
#pragma unroll
        for (int d4 = 0; d4 < 40; ++d4) {
          float4 a = *(const float4*)&Qr[d4*4];
          float4 c = *(const float4*)&Kr[d4*4];
          ax += a.x*c.x; ay += a.y*c.y; az += a.z*c.z; aw += a.w*c.w;
        }
        S[q*SMAX + jbase + j] = (ax+ay+az+aw) * scale;
      }
    }
  }
  __syncthreads();

  {
    int q = tid >> 4, i = tid & 15;
    float m = -INFINITY;
    if (q < nq)
      for (int j = i; j < L; j += 16) m = fmaxf(m, S[q*SMAX + j]);
    m = fmaxf(m, __shfl_xor(m, 1, 16));
    m = fmaxf(m, __shfl_xor(m, 2, 16));
    m = fmaxf(m, __shfl_xor(m, 4, 16));
    m = fmaxf(m, __shfl_xor(m, 8, 16));
    float s = 0.f;
    if (q < nq)
      for (int j = i; j < L; j += 16) {
        float e = expf(S[q*SMAX + j] - m);
        S[q*SMAX + j] = e; s += e;
      }
    s += __shfl_xor(s, 1, 16);
    s += __shfl_xor(s, 2, 16);
    s += __shfl_xor(s, 4, 16);
    s += __shfl_xor(s, 8, 16);
    float inv = 1.f / s;
    if (q < nq)
      for (int j = i; j < L; j += 16) S[q*SMAX + j] *= inv;
  }

  float o[10];
#pragma unroll
  for (int u = 0; u < 10; ++u) o[u] = 0.f;
  int q = tid >> 4, dg = tid & 15;
  for (int kt = 0; kt < nkt; ++kt) {
    int jbase = kt*KT;
    int nj = min(KT, L - jbase);
    __syncthreads();
    for (int idx = tid; idx < nj*40; idx += 256) {
      int j = idx/40, d4 = idx%40;
      *(float4*)&KVs[j*TSTR + d4*4] =
          *(const float4*)&vb[(size_t)(bo+jbase+j)*DIMS_ + d4*4];
    }
    __syncthreads();
    if (q < nq) {
      for (int j = 0; j < nj; ++j) {
        float w = S[q*SMAX + jbase + j];
        const float* Vr = &KVs[j*TSTR + dg];
#pragma unroll
        for (int u = 0; u < 10; ++u) o[u] += w * Vr[16*u];
      }
    }
  }
  if (q < nq) {
    float* Ar = &ab[(size_t)(bo+qbase+q)*DIMS_ + dg];
#pragma unroll
    for (int u = 0; u < 10; ++u) Ar[16*u] = o[u];
  }
}

// ---------------- inter-patch attention ----------------
__global__ __launch_bounds__(64)
void inter_attn(const float* __restrict__ qb, const float* __restrict__ kb,
                const float* __restrict__ vb, float* __restrict__ ab,
                const int* __restrict__ cnt, const int* __restrict__ offs,
                const int* __restrict__ cntmax) {
  int p = blockIdx.x, b = blockIdx.y;
  if (p >= cntmax[0]) return;
  int t = threadIdx.x;
  __shared__ int rows[8];
  __shared__ int nvs;
  __shared__ float w[8][9];
  if (t == 0) {
    int nv = 0;
    for (int r = 0; r < 8; ++r)
      if (p < cnt[r]) rows[nv++] = b*NNODES + offs[r] + p;
    nvs = nv;
  }
  __syncthreads();
  int nv = nvs;
  const float scale = 0.07905694150420949f;
  int i = t >> 3, j = t & 7;
  if (i < nv && j < nv) {
    const float4* qr = (const float4*)&qb[(size_t)rows[i]*DIMS_];
    const float4* kr = (const float4*)&kb[(size_t)rows[j]*DIMS_];
    float ax=0.f, ay=0.f, az=0.f, aw=0.f;
#pragma unroll
    for (int d4 = 0; d4 < 40; ++d4) {
      float4 a = qr[d4], c = kr[d4];
      ax += a.x*c.x; ay += a.y*c.y; az += a.z*c.z; aw += a.w*c.w;
    }
    w[i][j] = (ax+ay+az+aw) * scale;
  }
  __syncthreads();
  if (t < nv) {
    float m = -INFINITY;
    for (int jj = 0; jj < nv; ++jj) m = fmaxf(m, w[t][jj]);
    float s = 0.f;
    for (int jj = 0; jj < nv; ++jj) { float e = expf(w[t][jj] - m); w[t][jj] = e; s += e; }
    float inv = 1.0f / s;
    for (int jj = 0; jj < nv; ++jj) w[t][jj] *= inv;
  }
  __syncthreads();
  for (int d4 = t; d4 < 40; d4 += 64) {
    for (int i2 = 0; i2 < nv; ++i2) {
      float4 a = {0.f,0.f,0.f,0.f};
      for (int j2 = 0; j2 < nv; ++j2) {
        float ww = w[i2][j2];
        float4 v4 = *(const float4*)&vb[(size_t)rows[j2]*DIMS_ + d4*4];
        a.x += ww*v4.x; a.y += ww*v4.y; a.z += ww*v4.z; a.w += ww*v4.w;
      }
      *(float4*)&ab[(size_t)rows[i2]*DIMS_ + d4*4] = a;
    }
  }
}

// ---------------- final projection ----------------
__global__ __launch_bounds__(256)
void out_kernel(const float* __restrict__ pf, const float* __restrict__ outW,
                const float* __restrict__ outB, const int* __restrict__ pk,
                float* __restrict__ out) {
  int idx = blockIdx.x*256 + threadIdx.x;
  if (idx >= BB*12*NNODES) return;
  int n = idx % NNODES;
  int rest = idx / NNODES;
  int o = rest % 12;
  int b = rest / 12;
  int row = b*NNODES + pk[n];
  const float4* Pr = (const float4*)&pf[(size_t)row*DIMS_];
  const float4* Wr = (const float4*)&outW[o*DIMS_];
  float ax=0.f, ay=0.f, az=0.f, aw=0.f;
#pragma unroll
  for (int d4 = 0; d4 < 40; ++d4) {
    float4 a = Pr[d4], c = Wr[d4];
    ax += a.x*c.x; ay += a.y*c.y; az += a.z*c.z; aw += a.w*c.w;
  }
  out[idx] = (ax+ay+az+aw) + outB[o];
}

extern "C" void kernel_launch(void* const* d_in, const int* in_sizes, int n_in,
                              void* d_out, int out_size, void* d_ws, size_t ws_size,
                              hipStream_t stream) {
  const float* x         = (const float*)d_in[0];
  const int*   te        = (const int*)d_in[1];
  const float* patch_emb = (const float*)d_in[2];
  const float* node_tab  = (const float*)d_in[3];
  const float* tod_emb   = (const float*)d_in[4];
  const float* dow_emb   = (const float*)d_in[5];
  const float* conv_W    = (const float*)d_in[6];
  const float* conv_b    = (const float*)d_in[7];
  const float* ln_scale  = (const float*)d_in[8];
  const float* ln_bias   = (const float*)d_in[9];
  const float* attn_W    = (const float*)d_in[10];
  const float* attn_b    = (const float*)d_in[11];
  const float* mlp_W1    = (const float*)d_in[12];
  const float* mlp_b1    = (const float*)d_in[13];
  const float* mlp_W2    = (const float*)d_in[14];
  const float* mlp_b2    = (const float*)d_in[15];
  const float* out_W     = (const float*)d_in[16];
  const float* out_b     = (const float*)d_in[17];

  float* out = (float*)d_out;
  float* probs_st = out + BB*12*NNODES;

  float* ws = (float*)d_ws;
  float* pf  = ws;
  float* qb  = pf  + (size_t)RMAX*DIMS_;
  float* kb  = qb  + (size_t)RMAX*DIMS_;
  float* vb  = kb  + (size_t)RMAX*DIMS_;
  float* ab2 = vb  + (size_t)RMAX*DIMS_;
  float* hb  = ab2 + (size_t)RMAX*DIMS_;
  float* nsoft = hb + (size_t)RMAX*HID_;
  int* patch_ids = (int*)(nsoft + NNODES*32);
  int* pk     = patch_ids + NNODES;
  int* cnt    = pk + NNODES;
  int* offs   = cnt + 8;
  int* cntmax = offs + 8;

  patch_kernel<<<(NNODES + 127)/128, 128, 0, stream>>>(node_tab, patch_emb, probs_st, nsoft, patch_ids);
  scan_kernel<<<1, 1024, 0, stream>>>(patch_ids, pk, cnt, offs, cntmax);
  embed_kernel<<<dim3(NNODES, BB), 160, 0, stream>>>(x, te, conv_W, conv_b, tod_emb, dow_emb, nsoft, pk, pf);

  const int GRIDR = (RMAX + 31)/32;   // 221

  for (int l = 0; l < 3; ++l) {
    for (int a = 0; a < 2; ++a) {
      int wb = l*2 + a;
      const float* Wbase = attn_W + (size_t)wb*4*DIMS_*DIMS_;
      const float* bbase = attn_b + (size_t)wb*4*DIMS_;
      const float* g0 = ln_scale + (size_t)(l*4 + a*2)*DIMS_;
      const float* b0 = ln_bias  + (size_t)(l*4 + a*2)*DIMS_;
      const float* g1 = ln_scale + (size_t)(l*4 + a*2 + 1)*DIMS_;
      const float* b1 = ln_bias  + (size_t)(l*4 + a*2 + 1)*DIMS_;

      // QKV fused: y in {0,1,2} -> W offset, bias offset, output buffer offset
      matmul_ln<160,0,false,true><<<dim3(GRIDR,3), 256, 0, stream>>>(
          pf, Wbase, bbase, qb, g0, b0,
          RMAX, DIMS_, DIMS_,
          (size_t)DIMS_*DIMS_, (size_t)RMAX*DIMS_, DIMS_, 0);

      if (a == 0)
        intra_attn<<<dim3(SMAX/QT, 8, BB), 256, 0, stream>>>(qb, kb, vb, ab2, cnt, offs);
      else
        inter_attn<<<dim3(NNODES, BB), 64, 0, stream>>>(qb, kb, vb, ab2, cnt, offs, cntmax);

      // proj + residual into pf
      matmul_ln<160,0,true,false><<<dim3(GRIDR,1), 256, 0, stream>>>(
          ab2, Wbase + 3*DIMS_*DIMS_, bbase + 3*DIMS_, pf, nullptr, nullptr,
          RMAX, DIMS_, DIMS_, 0, 0, 0, 0);

      // MLP1: LN(pf) @ W1 -> hb (gelu); N=320 split over y in {0,1}
      matmul_ln<160,1,false,true><<<dim3(GRIDR,2), 256, 0, stream>>>(
          pf, mlp_W1 + (size_t)wb*DIMS_*HID_, mlp_b1 + (size_t)wb*HID_, hb, g1, b1,
          RMAX, HID_, HID_, 0, 0, 0, DIMS_);

      // MLP2: hb @ W2 + residual into pf
      matmul_ln<320,0,true,false><<<dim3(GRIDR,1), 256, 0, stream>>>(
          hb, mlp_W2 + (size_t)wb*HID_*DIMS_, mlp_b2 + (size_t)wb*DIMS_, pf, nullptr, nullptr,
          RMAX, DIMS_, DIMS_, 0, 0, 0, 0);
    }
  }

  out_kernel<<<(BB*12*NNODES + 255)/256, 256, 0, stream>>>(pf, out_W, out_b, pk, out);
}